// Round 12
// baseline (197.654 us; speedup 1.0000x reference)
//
#include <hip/hip_runtime.h>

// CvT block, MI355X bf16-MFMA implementation.
// B=32, C=128, L=32 (seq=1024), H=8, DK=64, HD=512, NLAYER=4.
// R22: non-attn traffic cuts. (a) out_gemm: one block per (b,ptb) computes
// BOTH ct halves (acc[2][4], 64KB dbuf w0f slices in LDS) -> att2 read once
// (67->33.5MB), 512 blocks. (b) prep xt2: write phase emits u16x8 16B
// stores (2/thread) instead of 16 scalar 2B stores. attn (R18, 81.5us),
// qkv (R21), prep bias/weight sections frozen.

#define NB   32
#define NH   8
#define SEQ  1024
#define DKH  64
#define HDIM 512
#define CIN  128

// 0.125 * log2(e): folded into Wq and bias so scores are in exp2 domain.
#define SCL 0.18033688011112042f

typedef __bf16 bf16x8 __attribute__((ext_vector_type(8)));
typedef float floatx4 __attribute__((ext_vector_type(4)));
typedef unsigned short u16x8 __attribute__((ext_vector_type(8)));
typedef unsigned int uintx4 __attribute__((ext_vector_type(4)));

__device__ __forceinline__ unsigned short f2bf(float f) {
    union { float f; unsigned int u; } c; c.f = f;
    unsigned int u = c.u;
    return (unsigned short)((u + 0x7fffu + ((u >> 16) & 1u)) >> 16); // RNE
}
__device__ __forceinline__ bf16x8 ldfrag(const unsigned short* p) {
    u16x8 v = *reinterpret_cast<const u16x8*>(p);
    return __builtin_bit_cast(bf16x8, v);
}
// pack two f32 -> two RNE bf16; 'a' lands in the LOW short.
__device__ __forceinline__ unsigned int pkbf(float a, float b) {
    unsigned int ua = __builtin_bit_cast(unsigned int, a);
    unsigned int ub = __builtin_bit_cast(unsigned int, b);
    ua += 0x7fffu + ((ua >> 16) & 1u);
    ub += 0x7fffu + ((ub >> 16) & 1u);
    return __builtin_amdgcn_perm(ub, ua, 0x07060302u);
}
// truncation pack (P>0): one v_perm, no rounding adds.
__device__ __forceinline__ unsigned int pkbf_t(float a, float b) {
    return __builtin_amdgcn_perm(__builtin_bit_cast(unsigned int, b),
                                 __builtin_bit_cast(unsigned int, a), 0x07060302u);
}
// async global->LDS, 16B per lane; LDS dest = wave-uniform base + lane*16.
__device__ __forceinline__ void g2l16(const void* g, void* l) {
    __builtin_amdgcn_global_load_lds((const __attribute__((address_space(1))) void*)g,
                                     (__attribute__((address_space(3))) void*)l, 16, 0, 0);
}

// Fragment-order storage: 512-elem block = one wave fragment [lane][j].
// Kf (A-frag, m=key): frag (s,c): lane (q,n) j <-> K[key=16s+n][d=32c+8q+j]
// Vf (A-frag, m=d, permuted k): frag (u,c): lane (q,n) jj <->
//     V[key = 32c+16(jj>>2)+4q+(jj&3)][d=16u+n]   (matches P^T pack order)

// ---------------- merged prep: bias Q4 table + weight casts + x transpose ----------------
// bids [0, 32): biasQ4[h][dxx][st][r] = R[h][dxx][(32-st-r)&31] * SCL
// bids [32, 1056): weight casts; Wq scaled by SCL (exp2 domain).
// bids [1056, 2080): xt2 = x transposed+scaled, vectorized u16x8 stores.
__global__ __launch_bounds__(256) void prep_all(const float* __restrict__ Wq,
                                                const float* __restrict__ Wk,
                                                const float* __restrict__ Wv,
                                                const float* __restrict__ W0,
                                                const float* __restrict__ R,
                                                const float* __restrict__ x,
                                                unsigned short* __restrict__ w2,
                                                unsigned short* __restrict__ w0f,
                                                float* __restrict__ biasQ4,
                                                unsigned short* __restrict__ xt2) {
    __shared__ float lds[64 * 65];
    int bid = blockIdx.x;
    if (bid < 32) {
        int idx4 = bid * 256 + threadIdx.x;            // [0, 8192) float4 slots
        int st = idx4 & 31, dxx = (idx4 >> 5) & 31, h = idx4 >> 10;
        const float* Rh = R + (h << 10) + (dxx << 5);
        floatx4 v;
        for (int r = 0; r < 4; ++r) v[r] = Rh[(32 - st - r) & 31] * SCL;
        *(floatx4*)&biasQ4[(size_t)idx4 * 4] = v;
    } else if (bid < 1056) {
        int idx = (bid - 32) * 256 + threadIdx.x;      // [0, 262144)
        if (idx < 196608) {
            int row = idx >> 7, col = idx & 127;
            float v;
            if (row < 512)       v = Wq[idx] * SCL;
            else if (row < 1024) v = Wk[idx - 65536];
            else                 v = Wv[idx - 131072];
            int rt = row >> 4, nr = row & 15, kc = col >> 5, qc = (col & 31) >> 3, jc = col & 7;
            w2[((rt * 4 + kc) * 512) + (qc * 16 + nr) * 8 + jc] = f2bf(v);
        } else {
            int idx2 = idx - 196608;
            int row = idx2 >> 9, col = idx2 & 511;
            int rt = row >> 4, nr = row & 15, kcA = col >> 5, qc = (col & 31) >> 3, jc = col & 7;
            w0f[((rt * 16 + kcA) * 512) + (qc * 16 + nr) * 8 + jc] = f2bf(W0[idx2]);
        }
    } else {
        int r = bid - 1056;                            // [0, 1024)
        int b = r & 31, yy = (r >> 5) & 1, zz = r >> 6;
        int c0 = yy * 64, p0 = zz * 64;
        int t = threadIdx.x, tr = t >> 6, tc = t & 63;
        const float inv_layer = 0.44721359549995793f;  // 1/sqrt(5)
        for (int rr = 0; rr < 16; ++rr) {
            int cl = rr * 4 + tr;
            lds[cl * 65 + tc] = x[(b * CIN + c0 + cl) * SEQ + p0 + tc];
        }
        __syncthreads();
        // write phase: each thread builds two 8-short rows (16B stores).
        // row ri: np=ri&15, qc=(ri>>4)&3, kc_l=(ri>>6)&1, pt_l=ri>>7;
        // value jc: channel-local cl = kc_l*32+qc*8+jc, pos-local = pt_l*16+np.
        int kc0 = c0 >> 5, pt0 = p0 >> 4;
        for (int rep = 0; rep < 2; ++rep) {
            int ri = rep * 256 + t;
            int np = ri & 15, qc = (ri >> 4) & 3, kc_l = (ri >> 6) & 1, pt_l = ri >> 7;
            int posl = pt_l * 16 + np;
            const float* lrow = &lds[(kc_l * 32 + qc * 8) * 65 + posl];
            u16x8 v;
#pragma unroll
            for (int jc = 0; jc < 8; ++jc)
                v[jc] = f2bf(lrow[jc * 65] * inv_layer);
            size_t addr = ((size_t)((b * 64 + pt0 + pt_l) * 4) + kc0 + kc_l) * 512
                          + (qc * 16 + np) * 8;
            *(u16x8*)&xt2[addr] = v;
        }
    }
}

// ---------------- fused QKV projection (R21, frozen) ----------------
__global__ __launch_bounds__(256, 2) void qkv_gemm(const unsigned short* __restrict__ xt2,
                                                   const unsigned short* __restrict__ w2,
                                                   unsigned short* __restrict__ Qt,
                                                   unsigned short* __restrict__ Kf,
                                                   unsigned short* __restrict__ Vf) {
    __shared__ alignas(16) unsigned short lds_s[16 * 512];   // 16 KB x tile
    int b = blockIdx.x, zt = blockIdx.y;
    int tid = threadIdx.x, wave = tid >> 6, lane = tid & 63, q = lane >> 4, n = lane & 15;

    const unsigned short* xsrc = xt2 + (size_t)(b * 64 + zt * 4) * 4 * 512;
    for (int i = 0; i < 4; ++i) {
        int f = wave * 4 + i;
        g2l16(xsrc + f * 512 + lane * 8, &lds_s[f * 512]);
    }
    __syncthreads();

    bf16x8 xf[16];
#pragma unroll
    for (int f = 0; f < 16; ++f) xf[f] = ldfrag(&lds_s[f * 512 + lane * 8]);

    int bh0 = b * NH;
    int pos0 = zt * 64;

    // ---- Q row-tiles (wrow 0..511) ----
    for (int y = 0; y < 8; ++y) {
        int rt = y * 4 + wave;
        const unsigned short* wbase = w2 + (size_t)rt * 4 * 512 + lane * 8;
        bf16x8 af[4];
#pragma unroll
        for (int kc = 0; kc < 4; ++kc) af[kc] = ldfrag(wbase + kc * 512);
        floatx4 acc[4];
#pragma unroll
        for (int s = 0; s < 4; ++s) acc[s] = (floatx4){0.f, 0.f, 0.f, 0.f};
#pragma unroll
        for (int kc = 0; kc < 4; ++kc)
#pragma unroll
            for (int s = 0; s < 4; ++s)
                acc[s] = __builtin_amdgcn_mfma_f32_16x16x32_bf16(af[kc], xf[s * 4 + kc], acc[s], 0, 0, 0);
        int wrow0 = y * 64 + wave * 16;
        int h = wrow0 >> 6;
        int d0 = (wrow0 & 63) + 4 * q;
#pragma unroll
        for (int s = 0; s < 4; ++s) {
            uint2 pk;
            pk.x = pkbf(acc[s][0], acc[s][1]);
            pk.y = pkbf(acc[s][2], acc[s][3]);
            int pos = pos0 + 16 * s + n;
            *(uint2*)&Qt[((size_t)(bh0 + h) * SEQ + pos) * DKH + d0] = pk;
        }
    }

    // ---- K row-tiles (wrow 512..1023) ----
    {
        int cd = wave >> 1;
        int qk = 2 * (wave & 1) + (q >> 1);
        int jk = 4 * (q & 1);
        for (int y = 8; y < 16; ++y) {
            int rt = y * 4 + wave;
            const unsigned short* wbase = w2 + (size_t)rt * 4 * 512 + lane * 8;
            bf16x8 af[4];
#pragma unroll
            for (int kc = 0; kc < 4; ++kc) af[kc] = ldfrag(wbase + kc * 512);
            floatx4 acc[4];
#pragma unroll
            for (int s = 0; s < 4; ++s) acc[s] = (floatx4){0.f, 0.f, 0.f, 0.f};
#pragma unroll
            for (int kc = 0; kc < 4; ++kc)
#pragma unroll
                for (int s = 0; s < 4; ++s)
                    acc[s] = __builtin_amdgcn_mfma_f32_16x16x32_bf16(af[kc], xf[s * 4 + kc], acc[s], 0, 0, 0);
            int wrow0 = y * 64 + wave * 16;
            int h = (wrow0 >> 6) - 8;
            int bh = bh0 + h;
#pragma unroll
            for (int s = 0; s < 4; ++s) {
                uint2 pk;
                pk.x = pkbf(acc[s][0], acc[s][1]);
                pk.y = pkbf(acc[s][2], acc[s][3]);
                size_t addr = ((size_t)(bh * 16 + zt) * 8 + s * 2 + cd) * 512
                              + (qk * 16 + n) * 8 + jk;
                *(uint2*)&Kf[addr] = pk;
            }
        }
    }

    // ---- V row-tiles (wrow 1024..1535): x = A operand, A-frags from LDS ----
    {
        int cj = wave >> 1;
        int jj0 = 4 * (wave & 1);
        const unsigned short* xlds = &lds_s[(wave * 4) * 512 + lane * 8];
        bf16x8 xa0 = ldfrag(xlds);
        bf16x8 xa1 = ldfrag(xlds + 512);
        bf16x8 xa2 = ldfrag(xlds + 1024);
        bf16x8 xa3 = ldfrag(xlds + 1536);
        for (int yv = 0; yv < 8; ++yv) {
            const unsigned short* wbase = w2 + (size_t)(64 + yv * 4) * 4 * 512 + lane * 8;
            floatx4 acc[4];
#pragma unroll
            for (int s = 0; s < 4; ++s) acc[s] = (floatx4){0.f, 0.f, 0.f, 0.f};
#pragma unroll
            for (int kc = 0; kc < 4; ++kc) {
                bf16x8 a_ = (kc == 0) ? xa0 : (kc == 1) ? xa1 : (kc == 2) ? xa2 : xa3;
                bf16x8 b0 = ldfrag(wbase + (0 * 4 + kc) * 512);
                bf16x8 b1 = ldfrag(wbase + (1 * 4 + kc) * 512);
                bf16x8 b2 = ldfrag(wbase + (2 * 4 + kc) * 512);
                bf16x8 b3 = ldfrag(wbase + (3 * 4 + kc) * 512);
                acc[0] = __builtin_amdgcn_mfma_f32_16x16x32_bf16(a_, b0, acc[0], 0, 0, 0);
                acc[1] = __builtin_amdgcn_mfma_f32_16x16x32_bf16(a_, b1, acc[1], 0, 0, 0);
                acc[2] = __builtin_amdgcn_mfma_f32_16x16x32_bf16(a_, b2, acc[2], 0, 0, 0);
                acc[3] = __builtin_amdgcn_mfma_f32_16x16x32_bf16(a_, b3, acc[3], 0, 0, 0);
            }
            int vrow0 = yv * 64;
#pragma unroll
            for (int s = 0; s < 4; ++s) {
                int vrow = vrow0 + 16 * s + n;
                int h = vrow >> 6, d = vrow & 63;
                int u = d >> 4, nl = d & 15;
                uint2 pk;
                pk.x = pkbf(acc[s][0], acc[s][1]);
                pk.y = pkbf(acc[s][2], acc[s][3]);
                size_t addr = ((size_t)((bh0 + h) * 16 + zt) * 8 + u * 2 + cj) * 512
                              + (q * 16 + nl) * 8 + jj0;
                *(uint2*)&Vf[addr] = pk;
            }
        }
    }
}

// ---------------- attention (4 qt/wave, 2 blocks/CU — R18 proven, untouched) ----------------
__global__ __launch_bounds__(256, 2) void attn_kernel(const unsigned short* __restrict__ Qt,
                                                      const unsigned short* __restrict__ Kf,
                                                      const unsigned short* __restrict__ Vf,
                                                      const float* __restrict__ biasQ4,
                                                      unsigned short* __restrict__ att2) {
    __shared__ alignas(16) unsigned short lds_k[2][8 * 512];   // 16 KB
    __shared__ alignas(16) unsigned short lds_v[2][8 * 512];   // 16 KB
    __shared__ alignas(16) float lds_bQ[4096];                 // 16 KB Q4 table

    int gid = blockIdx.x;
    int bh = gid & 255, qb = gid >> 8;                // qb in [0,4)
    int b = bh >> 3, h = bh & 7;
    int tid = threadIdx.x, wave = tid >> 6, lane = tid & 63, q = lane >> 4, n = lane & 15;
    int i0 = qb * 256 + wave * 64;
    int ti0 = i0 >> 4;

    const unsigned short* qbase = Qt + (size_t)bh * SEQ * DKH;
    const unsigned short* kft = Kf + (size_t)bh * 16 * 4096;
    const unsigned short* vft = Vf + (size_t)bh * 16 * 4096;
    int off0 = wave * 512;

    // ---- prologue: per-head Q4 table -> LDS; stage K/V tile 0 ----
    {
        const float* bQg = biasQ4 + (size_t)h * 4096;
        for (int i = 0; i < 4; ++i) {
            int fo = i * 1024 + wave * 256;           // wave-uniform float offset
            g2l16(bQg + fo + lane * 4, &lds_bQ[fo]);
        }
        g2l16(kft + off0 + lane * 8,        &lds_k[0][off0]);
        g2l16(kft + 2048 + off0 + lane * 8, &lds_k[0][2048 + off0]);
        g2l16(vft + off0 + lane * 8,        &lds_v[0][off0]);
        g2l16(vft + 2048 + off0 + lane * 8, &lds_v[0][2048 + off0]);
    }

    // Q as B-fragments: lane (q,n): query = i0+16qt+n, d = c*32+8q+j
    bf16x8 aq[4][2];
    for (int qt = 0; qt < 4; ++qt)
        for (int c = 0; c < 2; ++c)
            aq[qt][c] = ldfrag(qbase + (i0 + 16 * qt + n) * DKH + c * 32 + q * 8);

    floatx4 o[4][4];
    float lsum[4] = {0.f, 0.f, 0.f, 0.f};
    for (int qt = 0; qt < 4; ++qt)
        for (int u = 0; u < 4; ++u) o[qt][u] = (floatx4){0.f, 0.f, 0.f, 0.f};

    // bias gather: sv_s = Q4[dxx][st] (float4 = one b128).
    //   dxx = (ee + (qt>>1) - (s>>1)) & 31, ee = qb*8 + 2*wave - 2*kt;
    //   st = st0 if (s&1)==(qt&1) else st1 (per-lane column starts).
    int st0_4 = ((4 * q - n) & 31) * 4;
    int st1_4 = (((4 * q - n) + 16) & 31) * 4;
    int ee64 = qb * 8 + 2 * wave + 256;               // stays positive over kt

    __syncthreads();

// bias C-init for query tile qt (3 dxx bases: eh = ee+(qt>>1), el = eh-1)
#define LDB(qt, s0, s1, s2, s3) do {                                          \
        int eh_ = ee64 + ((qt) >> 1);                                         \
        int dh_ = (eh_ & 31) << 7;                                            \
        int dl_ = ((eh_ - 1) & 31) << 7;                                      \
        int sa_ = ((qt) & 1) ? st1_4 : st0_4;                                 \
        int sb_ = ((qt) & 1) ? st0_4 : st1_4;                                 \
        s0 = *(const floatx4*)&lds_bQ[dh_ + sa_];                             \
        s1 = *(const floatx4*)&lds_bQ[dh_ + sb_];                             \
        s2 = *(const floatx4*)&lds_bQ[dl_ + sa_];                             \
        s3 = *(const floatx4*)&lds_bQ[dl_ + sb_];                             \
    } while (0)

// S^T MFMA cluster for query tile qt
#define SMM(qt, s0, s1, s2, s3) do {                                          \
        s0 = __builtin_amdgcn_mfma_f32_16x16x32_bf16(kf2[0][0], aq[qt][0], s0, 0, 0, 0); \
        s0 = __builtin_amdgcn_mfma_f32_16x16x32_bf16(kf2[0][1], aq[qt][1], s0, 0, 0, 0); \
        s1 = __builtin_amdgcn_mfma_f32_16x16x32_bf16(kf2[1][0], aq[qt][0], s1, 0, 0, 0); \
        s1 = __builtin_amdgcn_mfma_f32_16x16x32_bf16(kf2[1][1], aq[qt][1], s1, 0, 0, 0); \
        s2 = __builtin_amdgcn_mfma_f32_16x16x32_bf16(kf2[2][0], aq[qt][0], s2, 0, 0, 0); \
        s2 = __builtin_amdgcn_mfma_f32_16x16x32_bf16(kf2[2][1], aq[qt][1], s2, 0, 0, 0); \
        s3 = __builtin_amdgcn_mfma_f32_16x16x32_bf16(kf2[3][0], aq[qt][0], s3, 0, 0, 0); \
        s3 = __builtin_amdgcn_mfma_f32_16x16x32_bf16(kf2[3][1], aq[qt][1], s3, 0, 0, 0); \
    } while (0)

// exp2 -> pack -> l partial -> O MFMA cluster for query tile qt
#define EPO(qt, s0, s1, s2, s3) do {                                          \
        floatx4 e0_, e1_, e2_, e3_;                                           \
        for (int r_ = 0; r_ < 4; ++r_) {                                      \
            e0_[r_] = __builtin_amdgcn_exp2f(s0[r_]);                         \
            e1_[r_] = __builtin_amdgcn_exp2f(s1[r_]);                         \
            e2_[r_] = __builtin_amdgcn_exp2f(s2[r_]);                         \
            e3_[r_] = __builtin_amdgcn_exp2f(s3[r_]);                         \
        }                                                                     \
        uintx4 pu0_, pu1_;                                                    \
        pu0_[0] = pkbf_t(e0_[0], e0_[1]);                                     \
        pu0_[1] = pkbf_t(e0_[2], e0_[3]);                                     \
        pu0_[2] = pkbf_t(e1_[0], e1_[1]);                                     \
        pu0_[3] = pkbf_t(e1_[2], e1_[3]);                                     \
        pu1_[0] = pkbf_t(e2_[0], e2_[1]);                                     \
        pu1_[1] = pkbf_t(e2_[2], e2_[3]);                                     \
        pu1_[2] = pkbf_t(e3_[0], e3_[1]);                                     \
        pu1_[3] = pkbf_t(e3_[2], e3_[3]);                                     \
        bf16x8 pf0_ = __builtin_bit_cast(bf16x8, pu0_);                       \
        bf16x8 pf1_ = __builtin_bit_cast(bf16x8, pu1_);                       \
        floatx4 es_ = (e0_ + e1_) + (e2_ + e3_);                              \
        lsum[qt] += (es_[0] + es_[1]) + (es_[2] + es_[3]);                    \
        o[qt][0] = __builtin_amdgcn_mfma_f32_16x16x32_bf16(vf2[0][0], pf0_, o[qt][0], 0, 0, 0); \
        o[qt][0] = __builtin_amdgcn_mfma_f32_16x16x32_bf16(vf2[0][1], pf1_, o[qt][0], 0, 0, 0); \
        o[qt][1] = __builtin_amdgcn_mfma_f32_16x16x32_bf16(vf2[1][0], pf0_, o[qt][1], 0, 0, 0); \
        o[qt][1] = __builtin_amdgcn_mfma_f32_16x16x32_bf16(vf2[1][1], pf1_, o[qt][1], 0, 0, 0); \
        o[qt][2] = __builtin_amdgcn_mfma_f32_16x16x32_bf16(vf2[2][0], pf0_, o[qt][2], 0, 0, 0); \
        o[qt][2] = __builtin_amdgcn_mfma_f32_16x16x32_bf16(vf2[2][1], pf1_, o[qt][2], 0, 0, 0); \
        o[qt][3] = __builtin_amdgcn_mfma_f32_16x16x32_bf16(vf2[3][0], pf0_, o[qt][3], 0, 0, 0); \
        o[qt][3] = __builtin_amdgcn_mfma_f32_16x16x32_bf16(vf2[3][1], pf1_, o[qt][3], 0, 0, 0); \
    } while (0)

    for (int kt = 0; kt < 16; ++kt) {
        int cur = kt & 1;

        // async stage next K/V tile
        if (kt < 15) {
            const unsigned short* kg = kft + (kt + 1) * 4096;
            const unsigned short* vg = vft + (kt + 1) * 4096;
            unsigned short* dk = &lds_k[cur ^ 1][0];
            unsigned short* dv = &lds_v[cur ^ 1][0];
            g2l16(kg + off0 + lane * 8,        dk + off0);
            g2l16(kg + 2048 + off0 + lane * 8, dk + 2048 + off0);
            g2l16(vg + off0 + lane * 8,        dv + off0);
            g2l16(vg + 2048 + off0 + lane * 8, dv + 2048 + off0);
        }

        // K,V fragments (shared across the 4 query tiles)
        bf16x8 kf2[4][2], vf2[4][2];
#pragma unroll
        for (int s = 0; s < 4; ++s)
#pragma unroll
            for (int c = 0; c < 2; ++c) {
                kf2[s][c] = ldfrag(&lds_k[cur][(s * 2 + c) * 512 + lane * 8]);
                vf2[s][c] = ldfrag(&lds_v[cur][(s * 2 + c) * 512 + lane * 8]);
            }

        floatx4 s0, s1, s2, s3;
        LDB(0, s0, s1, s2, s3);
        SMM(0, s0, s1, s2, s3);
        EPO(0, s0, s1, s2, s3);
        LDB(1, s0, s1, s2, s3);
        SMM(1, s0, s1, s2, s3);
        EPO(1, s0, s1, s2, s3);
        LDB(2, s0, s1, s2, s3);
        SMM(2, s0, s1, s2, s3);
        EPO(2, s0, s1, s2, s3);
        LDB(3, s0, s1, s2, s3);
        SMM(3, s0, s1, s2, s3);
        EPO(3, s0, s1, s2, s3);

        ee64 -= 2;
        __syncthreads();   // drains staged global_load_lds for kt+1 too
    }

#undef LDB
#undef SMM
#undef EPO

    // epilogue: reduce l across q-groups; O^T lane (q,n): query = i0+16qt+n,
    // d = 16u+4q+r -> att2 A-frag
    for (int qt = 0; qt < 4; ++qt) {
        float ls = lsum[qt];
        ls += __shfl_xor(ls, 16, 64);
        ls += __shfl_xor(ls, 32, 64);
        float inv = 1.0f / ls;
        int pt = ti0 + qt;
        for (int u = 0; u < 4; ++u) {
            int kcA = 2 * h + (u >> 1);
            int q2 = 2 * (u & 1) + (q >> 1);
            uint2 pk;
            pk.x = pkbf(o[qt][u][0] * inv, o[qt][u][1] * inv);
            pk.y = pkbf(o[qt][u][2] * inv, o[qt][u][3] * inv);
            size_t addr = ((size_t)((b * 64 + pt) * 16 + kcA) * 512)
                          + (q2 * 16 + n) * 8 + 4 * (q & 1);
            *(uint2*)&att2[addr] = pk;
        }
    }
}

// ---------------- output projection + residual (both ct halves per block) ----------------
// One block per (b,ptb): att2 row fragments read ONCE, both 64-channel
// halves computed (acc[2][4]); w0f g-slices (32 frags = 32KB) double-
// buffered in LDS via g2l16. 512 blocks, 64KB LDS -> 2 blocks/CU.
__global__ __launch_bounds__(256, 2) void out_gemm(const unsigned short* __restrict__ att2,
                                                   const unsigned short* __restrict__ w0f,
                                                   const float* __restrict__ x,
                                                   float* __restrict__ out) {
    __shared__ alignas(16) unsigned short lds_w[2][32 * 512];  // 2 x 32 KB
    int b = blockIdx.x, ptb = blockIdx.y;
    int tid = threadIdx.x, wave = tid >> 6, lane = tid & 63, q = lane >> 4, n = lane & 15;
    int pos0 = ptb * 64 + wave * 16;
    int pt = ptb * 4 + wave;
    const unsigned short* abase = att2 + (size_t)(b * 64 + pt) * 16 * 512 + lane * 8;
    floatx4 acc[2][4];
#pragma unroll
    for (int ct = 0; ct < 2; ++ct)
#pragma unroll
        for (int s = 0; s < 4; ++s) acc[ct][s] = (floatx4){0.f, 0.f, 0.f, 0.f};

    // stage g=0 slice: frag f = row*4+k2 (row = ct*4+s in 0..7)
    for (int i = 0; i < 8; ++i) {
        int f = wave * 8 + i;
        int row = f >> 2, k2 = f & 3;
        g2l16(w0f + ((size_t)row * 16 + k2) * 512 + lane * 8, &lds_w[0][f * 512]);
    }
    __syncthreads();

    for (int g = 0; g < 4; ++g) {
        int buf = g & 1;
        if (g < 3) {
            for (int i = 0; i < 8; ++i) {
                int f = wave * 8 + i;
                int row = f >> 2, k2 = f & 3;
                g2l16(w0f + ((size_t)row * 16 + (g + 1) * 4 + k2) * 512 + lane * 8,
                      &lds_w[buf ^ 1][f * 512]);
            }
        }
        bf16x8 af[4];
        for (int k2 = 0; k2 < 4; ++k2) af[k2] = ldfrag(abase + (g * 4 + k2) * 512);
#pragma unroll
        for (int k2 = 0; k2 < 4; ++k2)
#pragma unroll
            for (int r = 0; r < 8; ++r) {
                bf16x8 bf_ = ldfrag(&lds_w[buf][(r * 4 + k2) * 512 + lane * 8]);
                acc[r >> 2][r & 3] =
                    __builtin_amdgcn_mfma_f32_16x16x32_bf16(af[k2], bf_, acc[r >> 2][r & 3], 0, 0, 0);
            }
        __syncthreads();   // drains next-slice staging; separates buf reuse
    }

    int p0q = pos0 + 4 * q;
#pragma unroll
    for (int ct = 0; ct < 2; ++ct)
#pragma unroll
        for (int s = 0; s < 4; ++s) {
            int c = ct * 64 + 16 * s + n;
            size_t idx = ((size_t)b * CIN + c) * SEQ + p0q;
            floatx4 res = *(const floatx4*)&x[idx];
            floatx4 v = acc[ct][s] + res;
            *(floatx4*)&out[idx] = v;
        }
}

// ---------------- launch ----------------
extern "C" void kernel_launch(void* const* d_in, const int* in_sizes, int n_in,
                              void* d_out, int out_size, void* d_ws, size_t ws_size,
                              hipStream_t stream) {
    const float* x  = (const float*)d_in[0];
    const float* Wq = (const float*)d_in[1];
    const float* Wk = (const float*)d_in[2];
    const float* Wv = (const float*)d_in[3];
    const float* R  = (const float*)d_in[4];
    const float* W0 = (const float*)d_in[5];
    float* out = (float*)d_out;

    char* ws = (char*)d_ws;
    size_t off = 0;
    unsigned short* Qt   = (unsigned short*)(ws + off); off += (size_t)NB * NH * SEQ * DKH * 2;
    unsigned short* Kf   = (unsigned short*)(ws + off); off += (size_t)NB * NH * SEQ * DKH * 2;
    unsigned short* Vf   = (unsigned short*)(ws + off); off += (size_t)NB * NH * SEQ * DKH * 2;
    unsigned short* att2 = (unsigned short*)(ws + off); off += (size_t)NB * SEQ * HDIM * 2;
    unsigned short* xt2  = (unsigned short*)(ws + off); off += (size_t)NB * SEQ * CIN * 2;
    unsigned short* w2   = (unsigned short*)(ws + off); off += (size_t)1536 * 128 * 2;
    unsigned short* w0f  = (unsigned short*)(ws + off); off += (size_t)128 * 512 * 2;
    float* biasQ4 = (float*)(ws + off); off += (size_t)NH * 32 * 32 * 4 * 4;   // 128 KB
    (void)ws_size; (void)in_sizes; (void)n_in; (void)out_size;

    prep_all<<<2080, 256, 0, stream>>>(Wq, Wk, Wv, W0, R, x, w2, w0f, biasQ4, xt2);
    qkv_gemm<<<dim3(NB, 16), 256, 0, stream>>>(xt2, w2, Qt, Kf, Vf);
    attn_kernel<<<NB * NH * 4, 256, 0, stream>>>(Qt, Kf, Vf, biasQ4, att2);
    out_gemm<<<dim3(NB, 16), 256, 0, stream>>>(att2, w0f, x, out);
}

// Round 13
// 190.591 us; speedup vs baseline: 1.0371x; 1.0371x over previous
//
#include <hip/hip_runtime.h>

// CvT block, MI355X bf16-MFMA implementation.
// B=32, C=128, L=32 (seq=1024), H=8, DK=64, HD=512, NLAYER=4.
// R23: attn bias-read dedup. Budget analysis: attn is LDS-bandwidth-bound
// (52 b128-equiv/wave/kt x 12cy x 8 waves ~ 5000cy of the 6100cy kt-period;
// explains why occupancy/pipelining/vmcnt rounds were all null). The 16
// bias b128 LDB reads/kt are 4-fold redundant: all four qt C-inits draw
// from 6 distinct float4s (rows {ee-1,ee,ee+1} x cols {st0,st1}); qt1 =
// qt0 swapped, qt3 = qt2 swapped, qt2.low = qt0.high. MFMA's first chain
// link reads C without clobbering (D != C) -> zero-copy sharing. LDS
// instr 52 -> 42 (-19%). Numerics bit-identical.
// prep/qkv/out reverted to R19 exactly (best total 192.0; R21/R22 variants
// were neutral-to-negative).

#define NB   32
#define NH   8
#define SEQ  1024
#define DKH  64
#define HDIM 512
#define CIN  128

// 0.125 * log2(e): folded into Wq and bias so scores are in exp2 domain.
#define SCL 0.18033688011112042f

typedef __bf16 bf16x8 __attribute__((ext_vector_type(8)));
typedef float floatx4 __attribute__((ext_vector_type(4)));
typedef unsigned short u16x8 __attribute__((ext_vector_type(8)));
typedef unsigned int uintx4 __attribute__((ext_vector_type(4)));

__device__ __forceinline__ unsigned short f2bf(float f) {
    union { float f; unsigned int u; } c; c.f = f;
    unsigned int u = c.u;
    return (unsigned short)((u + 0x7fffu + ((u >> 16) & 1u)) >> 16); // RNE
}
__device__ __forceinline__ bf16x8 ldfrag(const unsigned short* p) {
    u16x8 v = *reinterpret_cast<const u16x8*>(p);
    return __builtin_bit_cast(bf16x8, v);
}
// pack two f32 -> two RNE bf16; 'a' lands in the LOW short.
__device__ __forceinline__ unsigned int pkbf(float a, float b) {
    unsigned int ua = __builtin_bit_cast(unsigned int, a);
    unsigned int ub = __builtin_bit_cast(unsigned int, b);
    ua += 0x7fffu + ((ua >> 16) & 1u);
    ub += 0x7fffu + ((ub >> 16) & 1u);
    return __builtin_amdgcn_perm(ub, ua, 0x07060302u);
}
// truncation pack (P>0): one v_perm, no rounding adds.
__device__ __forceinline__ unsigned int pkbf_t(float a, float b) {
    return __builtin_amdgcn_perm(__builtin_bit_cast(unsigned int, b),
                                 __builtin_bit_cast(unsigned int, a), 0x07060302u);
}
// async global->LDS, 16B per lane; LDS dest = wave-uniform base + lane*16.
__device__ __forceinline__ void g2l16(const void* g, void* l) {
    __builtin_amdgcn_global_load_lds((const __attribute__((address_space(1))) void*)g,
                                     (__attribute__((address_space(3))) void*)l, 16, 0, 0);
}

// Fragment-order storage: 512-elem block = one wave fragment [lane][j].
// Kf (A-frag, m=key): frag (s,c): lane (q,n) j <-> K[key=16s+n][d=32c+8q+j]
// Vf (A-frag, m=d, permuted k): frag (u,c): lane (q,n) jj <->
//     V[key = 32c+16(jj>>2)+4q+(jj&3)][d=16u+n]   (matches P^T pack order)

// ---------------- merged prep: bias Q4 table + weight casts + x transpose ----------------
// bids [0, 32): biasQ4[h][dxx][st][r] = R[h][dxx][(32-st-r)&31] * SCL
//   (pre-grouped float4 circulant rows; bias C-frag = Q4[dxx][st]).
// bids [32, 1056): weight casts; Wq scaled by SCL (exp2 domain).
// bids [1056, 2080): xt2 = x transposed+scaled into B/A fragment order.
__global__ __launch_bounds__(256) void prep_all(const float* __restrict__ Wq,
                                                const float* __restrict__ Wk,
                                                const float* __restrict__ Wv,
                                                const float* __restrict__ W0,
                                                const float* __restrict__ R,
                                                const float* __restrict__ x,
                                                unsigned short* __restrict__ w2,
                                                unsigned short* __restrict__ w0f,
                                                float* __restrict__ biasQ4,
                                                unsigned short* __restrict__ xt2) {
    __shared__ float lds[64 * 65];
    int bid = blockIdx.x;
    if (bid < 32) {
        int idx4 = bid * 256 + threadIdx.x;            // [0, 8192) float4 slots
        int st = idx4 & 31, dxx = (idx4 >> 5) & 31, h = idx4 >> 10;
        const float* Rh = R + (h << 10) + (dxx << 5);
        floatx4 v;
        for (int r = 0; r < 4; ++r) v[r] = Rh[(32 - st - r) & 31] * SCL;
        *(floatx4*)&biasQ4[(size_t)idx4 * 4] = v;
    } else if (bid < 1056) {
        int idx = (bid - 32) * 256 + threadIdx.x;      // [0, 262144)
        if (idx < 196608) {
            int row = idx >> 7, col = idx & 127;
            float v;
            if (row < 512)       v = Wq[idx] * SCL;
            else if (row < 1024) v = Wk[idx - 65536];
            else                 v = Wv[idx - 131072];
            int rt = row >> 4, nr = row & 15, kc = col >> 5, qc = (col & 31) >> 3, jc = col & 7;
            w2[((rt * 4 + kc) * 512) + (qc * 16 + nr) * 8 + jc] = f2bf(v);
        } else {
            int idx2 = idx - 196608;
            int row = idx2 >> 9, col = idx2 & 511;
            int rt = row >> 4, nr = row & 15, kcA = col >> 5, qc = (col & 31) >> 3, jc = col & 7;
            w0f[((rt * 16 + kcA) * 512) + (qc * 16 + nr) * 8 + jc] = f2bf(W0[idx2]);
        }
    } else {
        int r = bid - 1056;                            // [0, 1024)
        int b = r & 31, yy = (r >> 5) & 1, zz = r >> 6;
        int c0 = yy * 64, p0 = zz * 64;
        int t = threadIdx.x, tr = t >> 6, tc = t & 63;
        const float inv_layer = 0.44721359549995793f;  // 1/sqrt(5)
        for (int rr = 0; rr < 16; ++rr) {
            int cl = rr * 4 + tr;
            lds[cl * 65 + tc] = x[(b * CIN + c0 + cl) * SEQ + p0 + tc];
        }
        __syncthreads();
        for (int rr = 0; rr < 16; ++rr) {
            int pl = rr * 4 + tr;
            int pos = p0 + pl, c = c0 + tc;
            int pt = pos >> 4, np = pos & 15, kc = c >> 5, qc = (c & 31) >> 3, jc = c & 7;
            xt2[((size_t)((b * 64 + pt) * 4 + kc) * 512) + (qc * 16 + np) * 8 + jc] =
                f2bf(lds[tc * 65 + pl] * inv_layer);
        }
    }
}

// ---------------- fused QKV projection (R19, shared operand staged in LDS) ----------------
__global__ __launch_bounds__(256, 3) void qkv_gemm(const unsigned short* __restrict__ xt2,
                                                   const unsigned short* __restrict__ w2,
                                                   unsigned short* __restrict__ Qt,
                                                   unsigned short* __restrict__ Kf,
                                                   unsigned short* __restrict__ Vf) {
    __shared__ alignas(16) unsigned short lds_s[16 * 512];   // 16 KB shared tile
    int b = blockIdx.x, y = blockIdx.y, zt = blockIdx.z;
    int tid = threadIdx.x, wave = tid >> 6, lane = tid & 63, q = lane >> 4, n = lane & 15;
    floatx4 acc[4];
    for (int s = 0; s < 4; ++s) acc[s] = (floatx4){0.f, 0.f, 0.f, 0.f};
    bf16x8 af[4];

    if (y < 16) {
        // stage shared x tile (b, zt): frags f = s*4+kc
        const unsigned short* xsrc = xt2 + (size_t)(b * 64 + zt * 4) * 4 * 512;
        for (int i = 0; i < 4; ++i) {
            int f = wave * 4 + i;
            g2l16(xsrc + f * 512 + lane * 8, &lds_s[f * 512]);
        }
        int rt = y * 4 + wave;                       // per-wave w-row tile
        const unsigned short* wbase = w2 + (size_t)rt * 4 * 512 + lane * 8;
        for (int kc = 0; kc < 4; ++kc) af[kc] = ldfrag(wbase + kc * 512);
        __syncthreads();                             // drains g2l16 + af
#pragma unroll
        for (int kc = 0; kc < 4; ++kc) {
            bf16x8 b0 = ldfrag(&lds_s[(0 * 4 + kc) * 512 + lane * 8]);
            bf16x8 b1 = ldfrag(&lds_s[(1 * 4 + kc) * 512 + lane * 8]);
            bf16x8 b2 = ldfrag(&lds_s[(2 * 4 + kc) * 512 + lane * 8]);
            bf16x8 b3 = ldfrag(&lds_s[(3 * 4 + kc) * 512 + lane * 8]);
            acc[0] = __builtin_amdgcn_mfma_f32_16x16x32_bf16(af[kc], b0, acc[0], 0, 0, 0);
            acc[1] = __builtin_amdgcn_mfma_f32_16x16x32_bf16(af[kc], b1, acc[1], 0, 0, 0);
            acc[2] = __builtin_amdgcn_mfma_f32_16x16x32_bf16(af[kc], b2, acc[2], 0, 0, 0);
            acc[3] = __builtin_amdgcn_mfma_f32_16x16x32_bf16(af[kc], b3, acc[3], 0, 0, 0);
        }
        int wrow0 = y * 64 + wave * 16;
        int pos0 = zt * 64;
        if (y < 8) {
            int h = wrow0 >> 6;
            int d0 = (wrow0 & 63) + 4 * q;
            for (int s = 0; s < 4; ++s) {
                uint2 pk;
                pk.x = pkbf(acc[s][0], acc[s][1]);
                pk.y = pkbf(acc[s][2], acc[s][3]);
                int pos = pos0 + 16 * s + n;
                *(uint2*)&Qt[((size_t)(b * NH + h) * SEQ + pos) * DKH + d0] = pk;
            }
        } else {
            // K: d = wave*16+4q+r (regs), key = 16s+n. A-frag store.
            int h = (wrow0 >> 6) - 8;
            int bh = b * NH + h;
            int cd = wave >> 1;
            int qk = 2 * (wave & 1) + (q >> 1);
            int jk = 4 * (q & 1);
            for (int s = 0; s < 4; ++s) {
                uint2 pk;
                pk.x = pkbf(acc[s][0], acc[s][1]);
                pk.y = pkbf(acc[s][2], acc[s][3]);
                size_t addr = ((size_t)(bh * 16 + zt) * 8 + s * 2 + cd) * 512
                              + (qk * 16 + n) * 8 + jk;
                *(uint2*)&Kf[addr] = pk;
            }
        }
    } else {
        // stage shared w tile (V rows rtv0..rtv0+3): frags f = s*4+kc
        const unsigned short* wsrc = w2 + (size_t)(64 + (y - 16) * 4) * 4 * 512;
        for (int i = 0; i < 4; ++i) {
            int f = wave * 4 + i;
            g2l16(wsrc + f * 512 + lane * 8, &lds_s[f * 512]);
        }
        int pt = zt * 4 + wave;                      // per-wave pos tile
        const unsigned short* xbase = xt2 + (size_t)(b * 64 + pt) * 4 * 512 + lane * 8;
        for (int kc = 0; kc < 4; ++kc) af[kc] = ldfrag(xbase + kc * 512);
        __syncthreads();
#pragma unroll
        for (int kc = 0; kc < 4; ++kc) {
            bf16x8 b0 = ldfrag(&lds_s[(0 * 4 + kc) * 512 + lane * 8]);
            bf16x8 b1 = ldfrag(&lds_s[(1 * 4 + kc) * 512 + lane * 8]);
            bf16x8 b2 = ldfrag(&lds_s[(2 * 4 + kc) * 512 + lane * 8]);
            bf16x8 b3 = ldfrag(&lds_s[(3 * 4 + kc) * 512 + lane * 8]);
            acc[0] = __builtin_amdgcn_mfma_f32_16x16x32_bf16(af[kc], b0, acc[0], 0, 0, 0);
            acc[1] = __builtin_amdgcn_mfma_f32_16x16x32_bf16(af[kc], b1, acc[1], 0, 0, 0);
            acc[2] = __builtin_amdgcn_mfma_f32_16x16x32_bf16(af[kc], b2, acc[2], 0, 0, 0);
            acc[3] = __builtin_amdgcn_mfma_f32_16x16x32_bf16(af[kc], b3, acc[3], 0, 0, 0);
        }
        // V: key = wave*16+4q+r (regs) -> Vf A-frag with PV k-permutation.
        int vrow0 = (y - 16) * 64;
        int cj = wave >> 1;
        int jj0 = 4 * (wave & 1);
        for (int s = 0; s < 4; ++s) {
            int vrow = vrow0 + 16 * s + n;
            int h = vrow >> 6, d = vrow & 63;
            int u = d >> 4, nl = d & 15;
            uint2 pk;
            pk.x = pkbf(acc[s][0], acc[s][1]);
            pk.y = pkbf(acc[s][2], acc[s][3]);
            size_t addr = ((size_t)((b * NH + h) * 16 + zt) * 8 + u * 2 + cj) * 512
                          + (q * 16 + nl) * 8 + jj0;
            *(uint2*)&Vf[addr] = pk;
        }
    }
}

// ---------------- attention (4 qt/wave, 2 blocks/CU, deduped bias reads) ----------------
// WG = 256 queries (4 waves x 4 tiles of 16); key tiles of 64; grid 1024.
// Per kt, the 4 qt's bias C-inits draw from 6 shared float4s (3 circulant
// rows x 2 col-starts): qt0={B0,B1,C0,C1}, qt1 swapped, qt2={A0,A1,B0,B1},
// qt3 swapped. First MFMA of each chain reads the shared reg as C without
// clobbering it (D != C). LDS b128 reads: 16 -> 6 per kt per wave.
__global__ __launch_bounds__(256, 2) void attn_kernel(const unsigned short* __restrict__ Qt,
                                                      const unsigned short* __restrict__ Kf,
                                                      const unsigned short* __restrict__ Vf,
                                                      const float* __restrict__ biasQ4,
                                                      unsigned short* __restrict__ att2) {
    __shared__ alignas(16) unsigned short lds_k[2][8 * 512];   // 16 KB
    __shared__ alignas(16) unsigned short lds_v[2][8 * 512];   // 16 KB
    __shared__ alignas(16) float lds_bQ[4096];                 // 16 KB Q4 table

    int gid = blockIdx.x;
    int bh = gid & 255, qb = gid >> 8;                // qb in [0,4)
    int b = bh >> 3, h = bh & 7;
    int tid = threadIdx.x, wave = tid >> 6, lane = tid & 63, q = lane >> 4, n = lane & 15;
    int i0 = qb * 256 + wave * 64;
    int ti0 = i0 >> 4;

    const unsigned short* qbase = Qt + (size_t)bh * SEQ * DKH;
    const unsigned short* kft = Kf + (size_t)bh * 16 * 4096;
    const unsigned short* vft = Vf + (size_t)bh * 16 * 4096;
    int off0 = wave * 512;

    // ---- prologue: per-head Q4 table -> LDS; stage K/V tile 0 ----
    {
        const float* bQg = biasQ4 + (size_t)h * 4096;
        for (int i = 0; i < 4; ++i) {
            int fo = i * 1024 + wave * 256;           // wave-uniform float offset
            g2l16(bQg + fo + lane * 4, &lds_bQ[fo]);
        }
        g2l16(kft + off0 + lane * 8,        &lds_k[0][off0]);
        g2l16(kft + 2048 + off0 + lane * 8, &lds_k[0][2048 + off0]);
        g2l16(vft + off0 + lane * 8,        &lds_v[0][off0]);
        g2l16(vft + 2048 + off0 + lane * 8, &lds_v[0][2048 + off0]);
    }

    // Q as B-fragments: lane (q,n): query = i0+16qt+n, d = c*32+8q+j
    bf16x8 aq[4][2];
    for (int qt = 0; qt < 4; ++qt)
        for (int c = 0; c < 2; ++c)
            aq[qt][c] = ldfrag(qbase + (i0 + 16 * qt + n) * DKH + c * 32 + q * 8);

    floatx4 o[4][4];
    float lsum[4] = {0.f, 0.f, 0.f, 0.f};
    for (int qt = 0; qt < 4; ++qt)
        for (int u = 0; u < 4; ++u) o[qt][u] = (floatx4){0.f, 0.f, 0.f, 0.f};

    // bias rows: raw dxx rows used at tile kt are {ee-1, ee, ee+1},
    // ee = qb*8 + 2*wave - 2*kt; per-lane col starts st0/st1.
    int st0_4 = ((4 * q - n) & 31) * 4;
    int st1_4 = (((4 * q - n) + 16) & 31) * 4;
    int ee64 = qb * 8 + 2 * wave + 256;               // stays positive over kt

    __syncthreads();

// S^T MFMA cluster for query tile qt; chains INIT from shared bias regs
// (first link reads C without clobbering: D register differs from C).
#define SMM(qt, i0v, i1v, i2v, i3v, s0, s1, s2, s3) do {                      \
        s0 = __builtin_amdgcn_mfma_f32_16x16x32_bf16(kf2[0][0], aq[qt][0], i0v, 0, 0, 0); \
        s0 = __builtin_amdgcn_mfma_f32_16x16x32_bf16(kf2[0][1], aq[qt][1], s0, 0, 0, 0);  \
        s1 = __builtin_amdgcn_mfma_f32_16x16x32_bf16(kf2[1][0], aq[qt][0], i1v, 0, 0, 0); \
        s1 = __builtin_amdgcn_mfma_f32_16x16x32_bf16(kf2[1][1], aq[qt][1], s1, 0, 0, 0);  \
        s2 = __builtin_amdgcn_mfma_f32_16x16x32_bf16(kf2[2][0], aq[qt][0], i2v, 0, 0, 0); \
        s2 = __builtin_amdgcn_mfma_f32_16x16x32_bf16(kf2[2][1], aq[qt][1], s2, 0, 0, 0);  \
        s3 = __builtin_amdgcn_mfma_f32_16x16x32_bf16(kf2[3][0], aq[qt][0], i3v, 0, 0, 0); \
        s3 = __builtin_amdgcn_mfma_f32_16x16x32_bf16(kf2[3][1], aq[qt][1], s3, 0, 0, 0);  \
    } while (0)

// exp2 -> pack -> l partial -> O MFMA cluster for query tile qt
#define EPO(qt, s0, s1, s2, s3) do {                                          \
        floatx4 e0_, e1_, e2_, e3_;                                           \
        for (int r_ = 0; r_ < 4; ++r_) {                                      \
            e0_[r_] = __builtin_amdgcn_exp2f(s0[r_]);                         \
            e1_[r_] = __builtin_amdgcn_exp2f(s1[r_]);                         \
            e2_[r_] = __builtin_amdgcn_exp2f(s2[r_]);                         \
            e3_[r_] = __builtin_amdgcn_exp2f(s3[r_]);                         \
        }                                                                     \
        uintx4 pu0_, pu1_;                                                    \
        pu0_[0] = pkbf_t(e0_[0], e0_[1]);                                     \
        pu0_[1] = pkbf_t(e0_[2], e0_[3]);                                     \
        pu0_[2] = pkbf_t(e1_[0], e1_[1]);                                     \
        pu0_[3] = pkbf_t(e1_[2], e1_[3]);                                     \
        pu1_[0] = pkbf_t(e2_[0], e2_[1]);                                     \
        pu1_[1] = pkbf_t(e2_[2], e2_[3]);                                     \
        pu1_[2] = pkbf_t(e3_[0], e3_[1]);                                     \
        pu1_[3] = pkbf_t(e3_[2], e3_[3]);                                     \
        bf16x8 pf0_ = __builtin_bit_cast(bf16x8, pu0_);                       \
        bf16x8 pf1_ = __builtin_bit_cast(bf16x8, pu1_);                       \
        floatx4 es_ = (e0_ + e1_) + (e2_ + e3_);                              \
        lsum[qt] += (es_[0] + es_[1]) + (es_[2] + es_[3]);                    \
        o[qt][0] = __builtin_amdgcn_mfma_f32_16x16x32_bf16(vf2[0][0], pf0_, o[qt][0], 0, 0, 0); \
        o[qt][0] = __builtin_amdgcn_mfma_f32_16x16x32_bf16(vf2[0][1], pf1_, o[qt][0], 0, 0, 0); \
        o[qt][1] = __builtin_amdgcn_mfma_f32_16x16x32_bf16(vf2[1][0], pf0_, o[qt][1], 0, 0, 0); \
        o[qt][1] = __builtin_amdgcn_mfma_f32_16x16x32_bf16(vf2[1][1], pf1_, o[qt][1], 0, 0, 0); \
        o[qt][2] = __builtin_amdgcn_mfma_f32_16x16x32_bf16(vf2[2][0], pf0_, o[qt][2], 0, 0, 0); \
        o[qt][2] = __builtin_amdgcn_mfma_f32_16x16x32_bf16(vf2[2][1], pf1_, o[qt][2], 0, 0, 0); \
        o[qt][3] = __builtin_amdgcn_mfma_f32_16x16x32_bf16(vf2[3][0], pf0_, o[qt][3], 0, 0, 0); \
        o[qt][3] = __builtin_amdgcn_mfma_f32_16x16x32_bf16(vf2[3][1], pf1_, o[qt][3], 0, 0, 0); \
    } while (0)

    for (int kt = 0; kt < 16; ++kt) {
        int cur = kt & 1;

        // async stage next K/V tile
        if (kt < 15) {
            const unsigned short* kg = kft + (kt + 1) * 4096;
            const unsigned short* vg = vft + (kt + 1) * 4096;
            unsigned short* dk = &lds_k[cur ^ 1][0];
            unsigned short* dv = &lds_v[cur ^ 1][0];
            g2l16(kg + off0 + lane * 8,        dk + off0);
            g2l16(kg + 2048 + off0 + lane * 8, dk + 2048 + off0);
            g2l16(vg + off0 + lane * 8,        dv + off0);
            g2l16(vg + 2048 + off0 + lane * 8, dv + 2048 + off0);
        }

        // K,V fragments (shared across the 4 query tiles)
        bf16x8 kf2[4][2], vf2[4][2];
#pragma unroll
        for (int s = 0; s < 4; ++s)
#pragma unroll
            for (int c = 0; c < 2; ++c) {
                kf2[s][c] = ldfrag(&lds_k[cur][(s * 2 + c) * 512 + lane * 8]);
                vf2[s][c] = ldfrag(&lds_v[cur][(s * 2 + c) * 512 + lane * 8]);
            }

        // 6 shared bias C-inits: rows {ee (B), ee-1 (C)} first, {ee+1 (A)} later
        int r0_ = (ee64 & 31) << 7;
        int rm_ = ((ee64 - 1) & 31) << 7;
        floatx4 bB0 = *(const floatx4*)&lds_bQ[r0_ + st0_4];
        floatx4 bB1 = *(const floatx4*)&lds_bQ[r0_ + st1_4];
        floatx4 bC0 = *(const floatx4*)&lds_bQ[rm_ + st0_4];
        floatx4 bC1 = *(const floatx4*)&lds_bQ[rm_ + st1_4];

        floatx4 s0, s1, s2, s3;
        SMM(0, bB0, bB1, bC0, bC1, s0, s1, s2, s3);
        EPO(0, s0, s1, s2, s3);
        SMM(1, bB1, bB0, bC1, bC0, s0, s1, s2, s3);
        EPO(1, s0, s1, s2, s3);
        {
            int rp_ = ((ee64 + 1) & 31) << 7;
            floatx4 bA0 = *(const floatx4*)&lds_bQ[rp_ + st0_4];
            floatx4 bA1 = *(const floatx4*)&lds_bQ[rp_ + st1_4];
            SMM(2, bA0, bA1, bB0, bB1, s0, s1, s2, s3);
            EPO(2, s0, s1, s2, s3);
            SMM(3, bA1, bA0, bB1, bB0, s0, s1, s2, s3);
            EPO(3, s0, s1, s2, s3);
        }

        ee64 -= 2;
        __syncthreads();   // drains staged global_load_lds for kt+1 too
    }

#undef SMM
#undef EPO

    // epilogue: reduce l across q-groups; O^T lane (q,n): query = i0+16qt+n,
    // d = 16u+4q+r -> att2 A-frag
    for (int qt = 0; qt < 4; ++qt) {
        float ls = lsum[qt];
        ls += __shfl_xor(ls, 16, 64);
        ls += __shfl_xor(ls, 32, 64);
        float inv = 1.0f / ls;
        int pt = ti0 + qt;
        for (int u = 0; u < 4; ++u) {
            int kcA = 2 * h + (u >> 1);
            int q2 = 2 * (u & 1) + (q >> 1);
            uint2 pk;
            pk.x = pkbf(o[qt][u][0] * inv, o[qt][u][1] * inv);
            pk.y = pkbf(o[qt][u][2] * inv, o[qt][u][3] * inv);
            size_t addr = ((size_t)((b * 64 + pt) * 16 + kcA) * 512)
                          + (q2 * 16 + n) * 8 + 4 * (q & 1);
            *(uint2*)&att2[addr] = pk;
        }
    }
}

// ---------------- output projection + residual (R19, w0f g-slices staged in LDS) ----------------
__global__ __launch_bounds__(256, 3) void out_gemm(const unsigned short* __restrict__ att2,
                                                   const unsigned short* __restrict__ w0f,
                                                   const float* __restrict__ x,
                                                   float* __restrict__ out) {
    __shared__ alignas(16) unsigned short lds_w[2][16 * 512];  // 2 x 16 KB
    int b = blockIdx.x, ct = blockIdx.y, ptb = blockIdx.z;
    int tid = threadIdx.x, wave = tid >> 6, lane = tid & 63, q = lane >> 4, n = lane & 15;
    int pos0 = ptb * 64 + wave * 16;
    int c0 = ct * 64;
    int pt = ptb * 4 + wave;
    const unsigned short* abase = att2 + (size_t)(b * 64 + pt) * 16 * 512 + lane * 8;
    const unsigned short* wsrc = w0f + (size_t)(c0 >> 4) * 16 * 512;
    floatx4 acc[4];
    for (int s = 0; s < 4; ++s) acc[s] = (floatx4){0.f, 0.f, 0.f, 0.f};

    // stage g=0 slice: frag (s=wave, k2) -> lds slot (wave*4+k2)
    for (int k2 = 0; k2 < 4; ++k2)
        g2l16(wsrc + (wave * 16 + k2) * 512 + lane * 8, &lds_w[0][(wave * 4 + k2) * 512]);
    __syncthreads();

    for (int g = 0; g < 4; ++g) {
        int buf = g & 1;
        if (g < 3) {
            for (int k2 = 0; k2 < 4; ++k2)
                g2l16(wsrc + (wave * 16 + (g + 1) * 4 + k2) * 512 + lane * 8,
                      &lds_w[buf ^ 1][(wave * 4 + k2) * 512]);
        }
        bf16x8 af[4];
        for (int k2 = 0; k2 < 4; ++k2) af[k2] = ldfrag(abase + (g * 4 + k2) * 512);
#pragma unroll
        for (int k2 = 0; k2 < 4; ++k2) {
            bf16x8 b0 = ldfrag(&lds_w[buf][(0 * 4 + k2) * 512 + lane * 8]);
            bf16x8 b1 = ldfrag(&lds_w[buf][(1 * 4 + k2) * 512 + lane * 8]);
            bf16x8 b2 = ldfrag(&lds_w[buf][(2 * 4 + k2) * 512 + lane * 8]);
            bf16x8 b3 = ldfrag(&lds_w[buf][(3 * 4 + k2) * 512 + lane * 8]);
            acc[0] = __builtin_amdgcn_mfma_f32_16x16x32_bf16(af[k2], b0, acc[0], 0, 0, 0);
            acc[1] = __builtin_amdgcn_mfma_f32_16x16x32_bf16(af[k2], b1, acc[1], 0, 0, 0);
            acc[2] = __builtin_amdgcn_mfma_f32_16x16x32_bf16(af[k2], b2, acc[2], 0, 0, 0);
            acc[3] = __builtin_amdgcn_mfma_f32_16x16x32_bf16(af[k2], b3, acc[3], 0, 0, 0);
        }
        __syncthreads();   // drains next-slice staging; separates buf reuse
    }

    int p0q = pos0 + 4 * q;
    for (int s = 0; s < 4; ++s) {
        int c = c0 + 16 * s + n;
        size_t idx = ((size_t)b * CIN + c) * SEQ + p0q;
        floatx4 res = *(const floatx4*)&x[idx];
        floatx4 v = acc[s] + res;
        *(floatx4*)&out[idx] = v;
    }
}

// ---------------- launch ----------------
extern "C" void kernel_launch(void* const* d_in, const int* in_sizes, int n_in,
                              void* d_out, int out_size, void* d_ws, size_t ws_size,
                              hipStream_t stream) {
    const float* x  = (const float*)d_in[0];
    const float* Wq = (const float*)d_in[1];
    const float* Wk = (const float*)d_in[2];
    const float* Wv = (const float*)d_in[3];
    const float* R  = (const float*)d_in[4];
    const float* W0 = (const float*)d_in[5];
    float* out = (float*)d_out;

    char* ws = (char*)d_ws;
    size_t off = 0;
    unsigned short* Qt   = (unsigned short*)(ws + off); off += (size_t)NB * NH * SEQ * DKH * 2;
    unsigned short* Kf   = (unsigned short*)(ws + off); off += (size_t)NB * NH * SEQ * DKH * 2;
    unsigned short* Vf   = (unsigned short*)(ws + off); off += (size_t)NB * NH * SEQ * DKH * 2;
    unsigned short* att2 = (unsigned short*)(ws + off); off += (size_t)NB * SEQ * HDIM * 2;
    unsigned short* xt2  = (unsigned short*)(ws + off); off += (size_t)NB * SEQ * CIN * 2;
    unsigned short* w2   = (unsigned short*)(ws + off); off += (size_t)1536 * 128 * 2;
    unsigned short* w0f  = (unsigned short*)(ws + off); off += (size_t)128 * 512 * 2;
    float* biasQ4 = (float*)(ws + off); off += (size_t)NH * 32 * 32 * 4 * 4;   // 128 KB
    (void)ws_size; (void)in_sizes; (void)n_in; (void)out_size;

    prep_all<<<2080, 256, 0, stream>>>(Wq, Wk, Wv, W0, R, x, w2, w0f, biasQ4, xt2);
    qkv_gemm<<<dim3(NB, 24, 16), 256, 0, stream>>>(xt2, w2, Qt, Kf, Vf);
    attn_kernel<<<NB * NH * 4, 256, 0, stream>>>(Qt, Kf, Vf, biasQ4, att2);
    out_gemm<<<dim3(NB, 2, 16), 256, 0, stream>>>(att2, w0f, x, out);
}